// Round 2
// baseline (277.025 us; speedup 1.0000x reference)
//
#include <hip/hip_runtime.h>
#include <math.h>

#define S 1024
#define E 1024
#define H 32
#define KSEL 8
#define D 128
#define HD 4096      // H*D
#define SK 8192      // S*KSEL
#define MAXL 1024
#define CAP 9216     // SK + H*31 padding (per-head padded to 32)
#define ATTN_SCALE 0.08838834764831845f  // 1/sqrt(128)
#define SSTR 36
#define PSTR 40

#define NROUTER 256          // S/4 router blocks
#define NCONV 832            // 3*(8*32) + 8*8 transpose tiles (128x128)
#define NTAB 512             // rope-table builder blocks (no deps, ride along)
#define NQKV_T 1536          // qkv tickets (32h * 3proj * 16rt), h-major
#define NATTN_T 512          // attn tickets (32h * 16 qt-pairs), h-major
#define NTICK (NQKV_T + NATTN_T)

typedef _Float16 half8 __attribute__((ext_vector_type(8)));
typedef _Float16 half4 __attribute__((ext_vector_type(4)));
typedef float floatx16 __attribute__((ext_vector_type(16)));
typedef float f4 __attribute__((ext_vector_type(4)));

// async 16B global -> LDS (lands at wave-uniform base + lane*16)
#define GLOAD_LDS16(gsrc, ldst) \
    __builtin_amdgcn_global_load_lds( \
        (const __attribute__((address_space(1))) void*)(gsrc), \
        (__attribute__((address_space(3))) void*)(ldst), 16, 0, 0)

// ---------------- merged: router (VALU-bound) + weight transpose/convert (HBM-bound)
// + rope cos/sin table build (TRANS-bound) — three disjoint pipes, one dispatch.
__global__ __launch_bounds__(256) void router_conv_kernel(
    const float* __restrict__ x, const float* __restrict__ Wr,
    int* __restrict__ head_idx, float* __restrict__ head_w,
    float* __restrict__ pbuf, float* __restrict__ entz,
    _Float16* __restrict__ xh,
    const float* __restrict__ Wq, const float* __restrict__ Wk,
    const float* __restrict__ Wv, const float* __restrict__ Wo,
    _Float16* __restrict__ Wqkt, _Float16* __restrict__ Wot,
    float2* __restrict__ tab)
{
    int bid = blockIdx.x, tid = threadIdx.x;
    if (bid >= NROUTER + NCONV) {
        // ---- rope table: tab[p*64+d2] = {cos, sin}(p * 10000^(-d2/64)) ----
        int base = (bid - NROUTER - NCONV) * 1024;
        #pragma unroll
        for (int j = 0; j < 4; ++j) {
            int idx = base + j * 256 + tid;
            int p = idx >> 6, d2 = idx & 63;
            float inv = exp2f((float)d2 * -0.20762050f);
            float ang = (float)p * inv;
            float sn, cs;
            sincosf(ang, &sn, &cs);
            tab[idx] = make_float2(cs, sn);
        }
        return;
    }
    if (bid >= NROUTER) {
        // ---- 128x128 weight transpose+convert ----
        __shared__ _Float16 tl[128 * 128];
        int cb = bid - NROUTER;
        int z, rem;
        if (cb < 768) { z = cb >> 8; rem = cb & 255; }
        else          { z = 3;       rem = cb - 768; }
        const float* W = (z == 0) ? Wq : (z == 1) ? Wk : (z == 2) ? Wv : Wo;
        _Float16* T = (z < 3) ? (Wqkt + (size_t)z * HD * E) : Wot;
        int C = (z < 3) ? HD : 1024;
        int nc = C >> 7;
        int c0 = (rem % nc) * 128;
        int r0 = (rem / nc) * 128;
        #pragma unroll
        for (int p = 0; p < 16; ++p) {
            int idx = p * 256 + tid;
            int rr = idx >> 5, cg = (idx & 31) * 4;
            f4 v = *(const f4*)&W[(size_t)(r0 + rr) * C + c0 + cg];
            half4 o;
            o.x = (_Float16)v.x; o.y = (_Float16)v.y;
            o.z = (_Float16)v.z; o.w = (_Float16)v.w;
            int sc = cg ^ (((rr >> 3) & 7) << 2);
            *(half4*)&tl[rr * 128 + sc] = o;
        }
        __syncthreads();
        #pragma unroll
        for (int p = 0; p < 8; ++p) {
            int chunk = p * 256 + tid;
            int cc = chunk >> 4, ch = chunk & 15;
            int cidx = cc ^ ((ch & 7) << 2);
            half8 o;
            #pragma unroll
            for (int j = 0; j < 8; ++j)
                o[j] = tl[(ch * 8 + j) * 128 + cidx];
            *(half8*)&T[(size_t)(c0 + cc) * 1024 + r0 + ch * 8] = o;
        }
        return;
    }
    // ---- router: one wave per token + x->fp16 conversion fused ----
    int s = bid * 4 + (tid >> 6);
    int lane = tid & 63;
    int h = lane & 31, half = lane >> 5;
    const float* xr = x + (size_t)s * E + half * 512;
    const float* wr = Wr + (size_t)(half * 512) * H + h;
    float a0 = 0.f, a1 = 0.f, a2 = 0.f, a3 = 0.f;
    #pragma unroll 4
    for (int e = 0; e < 512; e += 4) {
        a0 += xr[e]     * wr[e * H];
        a1 += xr[e + 1] * wr[(e + 1) * H];
        a2 += xr[e + 2] * wr[(e + 2) * H];
        a3 += xr[e + 3] * wr[(e + 3) * H];
    }
    float acc = (a0 + a1) + (a2 + a3);
    acc += __shfl_xor(acc, 32, 64);
    float logit = acc;
    float m = logit;
    #pragma unroll
    for (int off = 16; off; off >>= 1) m = fmaxf(m, __shfl_xor(m, off, 64));
    float ex = expf(logit - m);
    float Z = ex;
    #pragma unroll
    for (int off = 16; off; off >>= 1) Z += __shfl_xor(Z, off, 64);
    float p = ex / Z;
    float es = p * logf(p + 1e-8f);
    #pragma unroll
    for (int off = 16; off; off >>= 1) es += __shfl_xor(es, off, 64);
    float lse = m + logf(Z);
    float lv = logit;
    float tv[KSEL]; int ti[KSEL];
    #pragma unroll
    for (int j = 0; j < KSEL; ++j) {
        float bv = lv; int bi = h;
        #pragma unroll
        for (int off = 16; off; off >>= 1) {
            float ov = __shfl_xor(bv, off, 64);
            int oi = __shfl_xor(bi, off, 64);
            if (ov > bv || (ov == bv && oi < bi)) { bv = ov; bi = oi; }
        }
        tv[j] = bv; ti[j] = bi;
        if (h == bi) lv = -INFINITY;
    }
    float Z2 = 0.f;
    #pragma unroll
    for (int j = 0; j < KSEL; ++j) Z2 += expf(tv[j] - tv[0]);
    if (lane < 32) pbuf[s * 32 + lane] = p;
    if (lane == 0) {
        entz[s * 2]     = es;
        entz[s * 2 + 1] = lse * lse;
        #pragma unroll
        for (int j = 0; j < KSEL; ++j) {
            head_idx[s * KSEL + j] = ti[j];
            head_w[s * KSEL + j]   = expf(tv[j] - tv[0]) / Z2;
        }
    }
    const float* xrow = x + (size_t)s * E;
    _Float16* xhrow = xh + (size_t)s * E;
    #pragma unroll
    for (int t = 0; t < 4; ++t) {
        int e = t * 256 + lane * 4;
        f4 v = *(const f4*)&xrow[e];
        half4 o;
        o.x = (_Float16)v.x; o.y = (_Float16)v.y; o.z = (_Float16)v.z; o.w = (_Float16)v.w;
        *(half4*)&xhrow[e] = o;
    }
}

// ---------------- scan (0..31) + aux (32, also zeroes the sync counters) ----------------
__global__ __launch_bounds__(256) void scan_aux_kernel(
    const int* __restrict__ head_idx, const int* __restrict__ head_counts,
    int* __restrict__ order, int* __restrict__ hlen, float* __restrict__ out_counts,
    const float* __restrict__ pbuf, const float* __restrict__ entz,
    float* __restrict__ out_aux, int* __restrict__ syncb)
{
    int bid = blockIdx.x, tid = threadIdx.x;
    if (bid == H) {
        if (tid < 40) syncb[tid] = 0;     // [0]=ticket, [1..32]=qdone per head
        int hh = tid & 31, grp = tid >> 5;
        __shared__ float red[256], red2[256];
        __shared__ float psum[32];
        __shared__ int hist[32];
        if (tid < 32) hist[tid] = 0;
        float ps = 0.f;
        for (int s = grp; s < S; s += 8) ps += pbuf[s * 32 + hh];
        red[tid] = ps;
        float es = 0.f, zs = 0.f;
        for (int s = tid; s < S; s += 256) { es += entz[s * 2]; zs += entz[s * 2 + 1]; }
        red2[tid] = es;
        __syncthreads();
        if (grp == 0) {
            float v = 0.f;
            #pragma unroll
            for (int j = 0; j < 8; ++j) v += red[j * 32 + hh];
            psum[hh] = v;
        }
        __syncthreads();
        red[tid] = zs;
        for (int s = tid; s < S; s += 256)
            atomicAdd(&hist[head_idx[s * KSEL]], 1);
        __syncthreads();
        for (int stp = 128; stp; stp >>= 1) {
            if (tid < stp) { red[tid] += red[tid + stp]; red2[tid] += red2[tid + stp]; }
            __syncthreads();
        }
        if (tid == 0) {
            float bal = 0.f;
            for (int j = 0; j < H; ++j)
                bal += ((float)hist[j] / (float)S) * (psum[j] / (float)S);
            bal *= (float)H;
            float ent_loss = red2[0] / (float)S;
            float z = red[0] / (float)S * 0.01f;
            out_aux[0] = 0.01f * bal + 0.01f * ent_loss + z;
        }
        return;
    }
    int h = bid;
    int wave = tid >> 6, lane = tid & 63;
    __shared__ int wtot[4][4];
    int base = 0;
    int hc = head_counts[h];
    int v0 = head_idx[tid],       v1 = head_idx[256 + tid];
    int v2 = head_idx[512 + tid], v3 = head_idx[768 + tid];
    unsigned long long lt = (1ull << lane) - 1ull;
    for (int c0 = 0; c0 < SK; c0 += 1024) {
        int n0 = 0, n1 = 0, n2 = 0, n3 = 0;
        if (c0 + 1024 < SK) {
            n0 = head_idx[c0 + 1024 + tid]; n1 = head_idx[c0 + 1280 + tid];
            n2 = head_idx[c0 + 1536 + tid]; n3 = head_idx[c0 + 1792 + tid];
        }
        bool p0 = (v0 == h), p1 = (v1 == h), p2 = (v2 == h), p3 = (v3 == h);
        unsigned long long m0 = __ballot(p0), m1 = __ballot(p1);
        unsigned long long m2 = __ballot(p2), m3 = __ballot(p3);
        int w0 = __popcll(m0 & lt), w1 = __popcll(m1 & lt);
        int w2 = __popcll(m2 & lt), w3 = __popcll(m3 & lt);
        if (lane == 0) {
            wtot[0][wave] = __popcll(m0); wtot[1][wave] = __popcll(m1);
            wtot[2][wave] = __popcll(m2); wtot[3][wave] = __popcll(m3);
        }
        __syncthreads();
        int pw[4], T[4];
        #pragma unroll
        for (int i = 0; i < 4; ++i) {
            int pre = 0, tot = 0;
            #pragma unroll
            for (int w = 0; w < 4; ++w) {
                int tv = wtot[i][w];
                if (w < wave) pre += tv;
                tot += tv;
            }
            pw[i] = pre; T[i] = tot;
        }
        if (p0) order[h * MAXL + base + pw[0] + w0] = c0 + tid;
        if (p1) order[h * MAXL + base + T[0] + pw[1] + w1] = c0 + 256 + tid;
        if (p2) order[h * MAXL + base + T[0] + T[1] + pw[2] + w2] = c0 + 512 + tid;
        if (p3) order[h * MAXL + base + T[0] + T[1] + T[2] + pw[3] + w3] = c0 + 768 + tid;
        base += T[0] + T[1] + T[2] + T[3];
        __syncthreads();
        v0 = n0; v1 = n1; v2 = n2; v3 = n3;
    }
    if (tid == 0) {
        hlen[h] = base;
        out_counts[h] = (float)(hc + base);
    }
}

// ================= fused qkv + attn, dynamic tickets + per-head flags =================
// LDS layout (35072 B): qkv path uses [0,32768) as Bs[2][128*64] f16 (and as 64x128 f32
// rope scratch). attn path: two independent halves at hh*17536:
//   [0,14592)  = Sld[2][32*36] f32 | Pld[2][32*40] f16 @9216 | alpha[2][32] @14336
//   [0,16384)  = Obuf[32][128] f32 (overlay, used only after all barriers)
//   [16384..]  = mlLd[32][4] | facLd[32][4] @16896 | flatLd[32] @17408

__device__ __forceinline__ void do_qkv_tile(
    int id, const _Float16* __restrict__ xh, const _Float16* __restrict__ Wt,
    const int* __restrict__ order, const int* __restrict__ hlen,
    const int* __restrict__ head_counts, const float2* __restrict__ tab,
    _Float16* __restrict__ qh, _Float16* __restrict__ kh, _Float16* __restrict__ vT,
    char* smem, int* syncb, int tid)
{
    int h = id / 48;
    int sub = id - h * 48;
    int qkv = sub >> 4;
    int rt = sub & 15;
    int len = hlen[h];
    int row0 = rt * 64;
    if (row0 >= len) return;
    int hb = 0;
    for (int i = 0; i < h; ++i) hb += (hlen[i] + 31) & ~31;
    int lenp = (len + 31) & ~31;
    int wave = tid >> 6, lane = tid & 63;
    int wm = wave >> 1, wn = wave & 1;
    int l32 = lane & 31, g = lane >> 5;

    _Float16* Bs = (_Float16*)smem;       // [2][128*64]

    int arow_g = row0 + wm * 32 + l32;
    int tok = (arow_g < len) ? (order[h * MAXL + arow_g] >> 3) : 0;
    const _Float16* aptr = xh + (size_t)tok * E;
    const _Float16* Wb = Wt + (size_t)((qkv * H + h) * D) * E;

    auto stageB = [&](int buf, int k0) {
        #pragma unroll
        for (int it = 0; it < 4; ++it) {
            int f = it * 256 + tid;
            int row = f >> 3, c = f & 7;
            int sc = c ^ (row & 7);
            const _Float16* src = Wb + (size_t)row * E + k0 + sc * 8;
            GLOAD_LDS16(src, &Bs[buf * 8192 + f * 8]);
        }
    };

    floatx16 acc[2] = {};
    half8 a_cur[4], a_nxt[4];
    #pragma unroll
    for (int ks = 0; ks < 4; ++ks)
        a_cur[ks] = *(const half8*)(aptr + ks * 16 + g * 8);

    auto compute = [&](int buf, half8* a) {
        #pragma unroll
        for (int ks = 0; ks < 4; ++ks) {
            int wchunk = ks * 2 + g;
            #pragma unroll
            for (int nf = 0; nf < 2; ++nf) {
                int brow = wn * 64 + nf * 32 + l32;
                half8 bf = *(const half8*)&Bs[buf * 8192 + brow * 64 + (wchunk ^ (brow & 7)) * 8];
                acc[nf] = __builtin_amdgcn_mfma_f32_32x32x16_f16(a[ks], bf, acc[nf], 0, 0, 0);
            }
        }
    };

    stageB(0, 0);
    __syncthreads();
    int buf = 0;
    for (int k0 = 64; k0 < E; k0 += 64) {
        stageB(buf ^ 1, k0);
        #pragma unroll
        for (int ks = 0; ks < 4; ++ks)
            a_nxt[ks] = *(const half8*)(aptr + k0 + ks * 16 + g * 8);
        compute(buf, a_cur);
        __syncthreads();
        buf ^= 1;
        #pragma unroll
        for (int ks = 0; ks < 4; ++ks) a_cur[ks] = a_nxt[ks];
    }
    compute(buf, a_cur);

    if (qkv < 2) {
        _Float16* dst = (qkv == 0) ? qh : kh;
        float* scr = (float*)smem;        // 64x128 f32 = 32KB
        __syncthreads();
        #pragma unroll
        for (int nf = 0; nf < 2; ++nf) {
            int col = wn * 64 + nf * 32 + l32;
            #pragma unroll
            for (int reg = 0; reg < 16; ++reg) {
                int rl = wm * 32 + (reg & 3) + 8 * (reg >> 2) + 4 * g;
                scr[rl * 128 + col] = acc[nf][reg];
            }
        }
        __syncthreads();
        int hc = head_counts[h];
        #pragma unroll
        for (int pass = 0; pass < 16; ++pass) {
            int idx = pass * 256 + tid;
            int r = idx >> 6, d2 = idx & 63;
            int slot = row0 + r;
            if (slot < len) {
                float v1 = scr[r * 128 + d2], v2 = scr[r * 128 + 64 + d2];
                int p = slot + hc;
                p = p < 0 ? 0 : (p > 8191 ? 8191 : p);
                float2 tt = tab[p * 64 + d2];
                _Float16* dp = dst + ((size_t)hb + slot) * D;
                dp[d2]      = (_Float16)(v1 * tt.x - v2 * tt.y);
                dp[d2 + 64] = (_Float16)(v2 * tt.x + v1 * tt.y);
            }
        }
    } else {
        #pragma unroll
        for (int nf = 0; nf < 2; ++nf) {
            int col = wn * 64 + nf * 32 + l32;
            #pragma unroll
            for (int q4 = 0; q4 < 4; ++q4) {
                int slot0 = row0 + wm * 32 + 8 * q4 + 4 * g;
                _Float16* vp = vT + (size_t)hb * D + (size_t)col * lenp + slot0;
                if (slot0 + 3 < len) {
                    half4 o;
                    o.x = (_Float16)acc[nf][q4 * 4 + 0];
                    o.y = (_Float16)acc[nf][q4 * 4 + 1];
                    o.z = (_Float16)acc[nf][q4 * 4 + 2];
                    o.w = (_Float16)acc[nf][q4 * 4 + 3];
                    *(half4*)vp = o;
                } else {
                    #pragma unroll
                    for (int r2 = 0; r2 < 4; ++r2)
                        if (slot0 + r2 < len) vp[r2] = (_Float16)acc[nf][q4 * 4 + r2];
                }
            }
        }
    }
    __syncthreads();   // drain all stores (vmcnt 0) before posting
    if (tid == 0)
        __hip_atomic_fetch_add(&syncb[1 + h], 1, __ATOMIC_RELEASE, __HIP_MEMORY_SCOPE_AGENT);
}

__device__ __forceinline__ void do_attn_pair(
    int id2, const _Float16* __restrict__ qh, const _Float16* __restrict__ kh,
    const _Float16* __restrict__ vT, const int* __restrict__ order,
    const int* __restrict__ hlen, const float* __restrict__ head_w,
    _Float16* __restrict__ ao, char* smem, int* syncb, int tid)
{
    int h = id2 >> 4, t = id2 & 15;
    int len = hlen[h];
    if (t * 64 >= len) return;
    int need = 3 * ((len + 63) >> 6);
    if (tid == 0) {
        while (__hip_atomic_load(&syncb[1 + h], __ATOMIC_ACQUIRE, __HIP_MEMORY_SCOPE_AGENT) < need)
            __builtin_amdgcn_s_sleep(2);
    }
    __syncthreads();

    int hh = tid >> 7;
    int lt = tid & 127;
    int wl = lt >> 6, lane = lt & 63;
    int l32 = lane & 31, g = lane >> 5;
    int srow = lane >> 1, shalf = lane & 1;

    char* hb_ = smem + hh * 17536;
    float* Sld = (float*)hb_;
    _Float16* Pld = (_Float16*)(hb_ + 9216);
    float* alphaLd = (float*)(hb_ + 14336);
    float* Obuf = (float*)hb_;
    float* mlLd = (float*)(hb_ + 16384);
    float* facLd = (float*)(hb_ + 16896);
    int* flatLd = (int*)(hb_ + 17408);

    int qt = t * 2 + hh;
    int row0 = qt * 32;
    bool alive = row0 < len;
    int row0c = alive ? row0 : 0;

    int hb = 0;
    for (int i = 0; i < h; ++i) hb += (hlen[i] + 31) & ~31;
    int lenp = (len + 31) & ~31;

    if (lt < 32) {
        int r = row0 + lt;
        flatLd[lt] = (alive && r < len) ? order[h * MAXL + r] : -1;
    }

    const _Float16* qrow = qh + ((size_t)hb + row0c + l32) * D;
    half8 qf[8];
    #pragma unroll
    for (int tt = 0; tt < 8; ++tt) qf[tt] = *(const half8*)(qrow + tt * 16 + g * 8);

    floatx16 O[4] = {};
    float m_run = -INFINITY, l_run = 0.f;

    if (alive && wl <= qt) {
        half8 kf[8], kfn[8], vv[8];
        {
            const _Float16* krow = kh + ((size_t)hb + wl * 32 + l32) * D;
            #pragma unroll
            for (int tt = 0; tt < 8; ++tt) kf[tt] = *(const half8*)(krow + tt * 16 + g * 8);
        }
        for (int kt = wl; kt <= qt; kt += 2) {
            int col0 = kt * 32;
            floatx16 Sc = {};
            #pragma unroll
            for (int tt = 0; tt < 8; ++tt)
                Sc = __builtin_amdgcn_mfma_f32_32x32x16_f16(qf[tt], kf[tt], Sc, 0, 0, 0);
            #pragma unroll
            for (int nt = 0; nt < 4; ++nt) {
                const _Float16* vp = vT + (size_t)hb * D + (size_t)(nt * 32 + l32) * lenp + col0;
                vv[nt * 2]     = *(const half8*)(vp + g * 8);
                vv[nt * 2 + 1] = *(const half8*)(vp + 16 + g * 8);
            }
            if (kt + 2 <= qt) {
                const _Float16* krow = kh + ((size_t)hb + col0 + 64 + l32) * D;
                #pragma unroll
                for (int tt = 0; tt < 8; ++tt) kfn[tt] = *(const half8*)(krow + tt * 16 + g * 8);
            }
            bool diag = (kt == qt);
            #pragma unroll
            for (int reg = 0; reg < 16; ++reg) {
                int row = (reg & 3) + 8 * (reg >> 2) + 4 * g;
                float s = Sc[reg] * ATTN_SCALE;
                if (diag && l32 > row) s = -1e30f;
                Sld[wl * (32 * SSTR) + row * SSTR + l32] = s;
            }
            __builtin_amdgcn_wave_barrier();
            const float* sp = &Sld[wl * (32 * SSTR) + srow * SSTR + shalf * 16];
            float va[16];
            *(f4*)(va)      = *(const f4*)(sp);
            *(f4*)(va + 4)  = *(const f4*)(sp + 4);
            *(f4*)(va + 8)  = *(const f4*)(sp + 8);
            *(f4*)(va + 12) = *(const f4*)(sp + 12);
            float mt_ = va[0];
            #pragma unroll
            for (int j = 1; j < 16; ++j) mt_ = fmaxf(mt_, va[j]);
            mt_ = fmaxf(mt_, __shfl_xor(mt_, 1, 64));
            float m_new = fmaxf(m_run, mt_);
            float alpha = __expf(m_run - m_new);
            float p[16], tsum = 0.f;
            #pragma unroll
            for (int j = 0; j < 16; ++j) { p[j] = __expf(va[j] - m_new); tsum += p[j]; }
            tsum += __shfl_xor(tsum, 1, 64);
            l_run = l_run * alpha + tsum;
            m_run = m_new;
            half8 ph0, ph1;
            #pragma unroll
            for (int j = 0; j < 8; ++j) { ph0[j] = (_Float16)p[j]; ph1[j] = (_Float16)p[j + 8]; }
            *(half8*)&Pld[wl * (32 * PSTR) + srow * PSTR + shalf * 16]     = ph0;
            *(half8*)&Pld[wl * (32 * PSTR) + srow * PSTR + shalf * 16 + 8] = ph1;
            if (shalf == 0) alphaLd[wl * 32 + srow] = alpha;
            __builtin_amdgcn_wave_barrier();
            f4 al[4];
            #pragma unroll
            for (int qq = 0; qq < 4; ++qq) al[qq] = *(const f4*)&alphaLd[wl * 32 + 4 * g + 8 * qq];
            #pragma unroll
            for (int reg = 0; reg < 16; ++reg) {
                float av = al[reg >> 2][reg & 3];
                O[0][reg] *= av; O[1][reg] *= av; O[2][reg] *= av; O[3][reg] *= av;
            }
            half8 pf0 = *(const half8*)&Pld[wl * (32 * PSTR) + l32 * PSTR + g * 8];
            half8 pf1 = *(const half8*)&Pld[wl * (32 * PSTR) + l32 * PSTR + 16 + g * 8];
            #pragma unroll
            for (int nt = 0; nt < 4; ++nt) {
                O[nt] = __builtin_amdgcn_mfma_f32_32x32x16_f16(pf0, vv[nt * 2],     O[nt], 0, 0, 0);
                O[nt] = __builtin_amdgcn_mfma_f32_32x32x16_f16(pf1, vv[nt * 2 + 1], O[nt], 0, 0, 0);
            }
            __builtin_amdgcn_wave_barrier();
            #pragma unroll
            for (int tt = 0; tt < 8; ++tt) kf[tt] = kfn[tt];
        }
    }
    if (shalf == 0) { mlLd[srow * 4 + wl * 2] = m_run; mlLd[srow * 4 + wl * 2 + 1] = l_run; }
    __syncthreads();
    if (lt < 32) {
        float m0 = mlLd[lt * 4 + 0], l0 = mlLd[lt * 4 + 1];
        float m1 = mlLd[lt * 4 + 2], l1 = mlLd[lt * 4 + 3];
        float ms = fmaxf(m0, m1);
        float f0 = __expf(m0 - ms), f1 = __expf(m1 - ms);
        float ltn = f0 * l0 + f1 * l1;
        int flat = flatLd[lt];
        float hw = (flat >= 0) ? head_w[flat] : 0.f;
        facLd[lt * 4 + 0] = f1;
        facLd[lt * 4 + 1] = hw / ltn;
        facLd[lt * 4 + 2] = f0;
    }
    __syncthreads();
    if (wl == 1) {
        #pragma unroll
        for (int nt = 0; nt < 4; ++nt) {
            int col = nt * 32 + l32;
            #pragma unroll
            for (int reg = 0; reg < 16; ++reg) {
                int row = (reg & 3) + 8 * (reg >> 2) + 4 * g;
                Obuf[row * 128 + col] = O[nt][reg] * facLd[row * 4 + 0];
            }
        }
    }
    __syncthreads();
    if (wl == 0) {
        #pragma unroll
        for (int nt = 0; nt < 4; ++nt) {
            int col = nt * 32 + l32;
            #pragma unroll
            for (int reg = 0; reg < 16; ++reg) {
                int row = (reg & 3) + 8 * (reg >> 2) + 4 * g;
                int flat = flatLd[row];
                if (flat >= 0) {
                    float val = (O[nt][reg] * facLd[row * 4 + 2] + Obuf[row * 128 + col]) * facLd[row * 4 + 1];
                    ao[(size_t)flat * D + col] = (_Float16)val;
                }
            }
        }
    }
}

__global__ __launch_bounds__(256) void qkv_attn(
    const _Float16* __restrict__ xh, const _Float16* __restrict__ Wt,
    const int* __restrict__ order, const int* __restrict__ hlen,
    const int* __restrict__ head_counts, const float2* __restrict__ tab,
    _Float16* __restrict__ qh, _Float16* __restrict__ kh, _Float16* __restrict__ vT,
    const float* __restrict__ head_w, _Float16* __restrict__ ao,
    int* __restrict__ syncb)
{
    __shared__ __align__(16) char smem[35072];
    __shared__ int sh_id;
    int tid = threadIdx.x;
    while (true) {
        __syncthreads();
        if (tid == 0)
            sh_id = __hip_atomic_fetch_add(&syncb[0], 1, __ATOMIC_RELAXED, __HIP_MEMORY_SCOPE_AGENT);
        __syncthreads();
        int id = sh_id;
        if (id >= NTICK) break;
        if (id < NQKV_T)
            do_qkv_tile(id, xh, Wt, order, hlen, head_counts, tab, qh, kh, vT, smem, syncb, tid);
        else
            do_attn_pair(id - NQKV_T, qh, kh, vT, order, hlen, head_w, ao, smem, syncb, tid);
    }
}

// ---------------- output projection: B-only LDS dbuf MFMA GEMM, A direct-to-reg ----------------
__global__ __launch_bounds__(256) void out_mfma(
    const _Float16* __restrict__ A, const _Float16* __restrict__ Bt,
    float* __restrict__ C)
{
    int n0 = blockIdx.x * 64, m0 = blockIdx.y * 64;
    int tid = threadIdx.x, wave = tid >> 6, lane = tid & 63;
    int wm = wave >> 1, wn = wave & 1;
    int l32 = lane & 31, g = lane >> 5;

    __shared__ _Float16 Bs[2][64 * 64];

    const _Float16* aptr = A + (size_t)(m0 + wm * 32 + l32) * 1024;

    auto stageB = [&](int buf, int k0) {
        #pragma unroll
        for (int it = 0; it < 2; ++it) {
            int f = it * 256 + tid;
            int row = f >> 3, c = f & 7;
            int sc = c ^ (row & 7);
            GLOAD_LDS16(Bt + (size_t)(n0 + row) * 1024 + k0 + sc * 8, &Bs[buf][f * 8]);
        }
    };

    floatx16 acc = {};
    int brow = wn * 32 + l32;
    half8 a_cur[4], a_nxt[4];
    #pragma unroll
    for (int ks = 0; ks < 4; ++ks)
        a_cur[ks] = *(const half8*)(aptr + ks * 16 + g * 8);

    auto compute = [&](int buf, half8* a) {
        #pragma unroll
        for (int ks = 0; ks < 4; ++ks) {
            int wchunk = ks * 2 + g;
            half8 bf = *(const half8*)&Bs[buf][brow * 64 + (wchunk ^ (brow & 7)) * 8];
            acc = __builtin_amdgcn_mfma_f32_32x32x16_f16(a[ks], bf, acc, 0, 0, 0);
        }
    };

    stageB(0, 0);
    __syncthreads();
    int buf = 0;
    for (int k0 = 64; k0 < 1024; k0 += 64) {
        stageB(buf ^ 1, k0);
        #pragma unroll
        for (int ks = 0; ks < 4; ++ks)
            a_nxt[ks] = *(const half8*)(aptr + k0 + ks * 16 + g * 8);
        compute(buf, a_cur);
        __syncthreads();
        buf ^= 1;
        #pragma unroll
        for (int ks = 0; ks < 4; ++ks) a_cur[ks] = a_nxt[ks];
    }
    compute(buf, a_cur);

    int col = n0 + wn * 32 + l32;
    #pragma unroll
    for (int reg = 0; reg < 16; ++reg) {
        int row = m0 + wm * 32 + (reg & 3) + 8 * (reg >> 2) + 4 * g;
        C[(size_t)row * 1024 + col] = acc[reg];
    }
}

extern "C" void kernel_launch(void* const* d_in, const int* in_sizes, int n_in,
                              void* d_out, int out_size, void* d_ws, size_t ws_size,
                              hipStream_t stream)
{
    const float* x  = (const float*)d_in[0];
    const float* Wq = (const float*)d_in[1];
    const float* Wk = (const float*)d_in[2];
    const float* Wv = (const float*)d_in[3];
    const float* Wr = (const float*)d_in[4];
    const float* Wo = (const float*)d_in[5];
    const int* head_counts = (const int*)d_in[6];
    float* out = (float*)d_out;

    float* head_w = (float*)d_ws;                 // SK
    float* pbuf   = head_w + SK;                  // S*32
    float* entz   = pbuf + S * 32;                // S*2
    int* head_idx = (int*)(entz + S * 2);         // SK
    int* order    = head_idx + SK;                // H*MAXL
    int* hlen     = order + H * MAXL;             // 32 (pad 64)
    _Float16* xh   = (_Float16*)(hlen + 64);      // S*E
    _Float16* aoh  = xh + (size_t)S * E;          // SK*D
    _Float16* Wqkt = aoh + (size_t)SK * D;        // 3*HD*E
    _Float16* Wot  = Wqkt + (size_t)3 * HD * E;   // 1024*1024
    _Float16* qh   = Wot + (size_t)1024 * 1024;   // CAP*D
    _Float16* kh   = qh + (size_t)CAP * D;        // CAP*D
    _Float16* vT   = kh + (size_t)CAP * D;        // CAP*D
    float2* tab    = (float2*)(vT + (size_t)CAP * D);   // 8192*64 float2 = 4MB
    int* syncb     = (int*)(tab + (size_t)8192 * 64);   // [0]=ticket, [1..32]=qdone

    router_conv_kernel<<<NROUTER + NCONV + NTAB, 256, 0, stream>>>(
        x, Wr, head_idx, head_w, pbuf, entz, xh, Wq, Wk, Wv, Wo, Wqkt, Wot, tab);
    scan_aux_kernel<<<33, 256, 0, stream>>>(head_idx, head_counts, order, hlen,
                                            out + (size_t)S * E, pbuf, entz,
                                            out + (size_t)S * E + H, syncb);
    qkv_attn<<<1024, 256, 0, stream>>>(xh, Wqkt, order, hlen, head_counts, tab,
                                       qh, kh, vT, head_w, aoh, syncb);
    out_mfma<<<dim3(16, 16), 256, 0, stream>>>(aoh, Wot, out);
}

// Round 3
// 222.054 us; speedup vs baseline: 1.2476x; 1.2476x over previous
//
#include <hip/hip_runtime.h>
#include <math.h>

#define S 1024
#define E 1024
#define H 32
#define KSEL 8
#define D 128
#define HD 4096      // H*D
#define SK 8192      // S*KSEL
#define MAXL 1024
#define CAP 9216     // SK + H*31 padding (per-head padded to 32)
#define ATTN_SCALE 0.08838834764831845f  // 1/sqrt(128)
#define SSTR 36
#define PSTR 40

#define NROUTER 256          // S/4 router blocks
#define NCONV 64             // Wo-only transpose tiles (128x128)
#define NTAB 512             // rope-table builder blocks (no deps, ride along)

typedef _Float16 half8 __attribute__((ext_vector_type(8)));
typedef _Float16 half4 __attribute__((ext_vector_type(4)));
typedef float floatx16 __attribute__((ext_vector_type(16)));
typedef float f4 __attribute__((ext_vector_type(4)));

// async 16B global -> LDS (lands at wave-uniform base + lane*16)
#define GLOAD_LDS16(gsrc, ldst) \
    __builtin_amdgcn_global_load_lds( \
        (const __attribute__((address_space(1))) void*)(gsrc), \
        (__attribute__((address_space(3))) void*)(ldst), 16, 0, 0)

// ---------------- merged: router (VALU-bound) + Wo transpose/convert (HBM-bound)
// + rope cos/sin table build (TRANS-bound) — disjoint pipes, one dispatch.
__global__ __launch_bounds__(256) void router_conv_kernel(
    const float* __restrict__ x, const float* __restrict__ Wr,
    int* __restrict__ head_idx, float* __restrict__ head_w,
    float* __restrict__ pbuf, float* __restrict__ entz,
    _Float16* __restrict__ xh,
    const float* __restrict__ Wo, _Float16* __restrict__ Wot,
    float2* __restrict__ tab)
{
    int bid = blockIdx.x, tid = threadIdx.x;
    if (bid >= NROUTER + NCONV) {
        // ---- rope table: tab[p*64+d2] = {cos, sin}(p * 10000^(-d2/64)) ----
        int base = (bid - NROUTER - NCONV) * 1024;
        #pragma unroll
        for (int j = 0; j < 4; ++j) {
            int idx = base + j * 256 + tid;
            int p = idx >> 6, d2 = idx & 63;
            float inv = exp2f((float)d2 * -0.20762050f);
            float ang = (float)p * inv;
            float sn, cs;
            sincosf(ang, &sn, &cs);
            tab[idx] = make_float2(cs, sn);
        }
        return;
    }
    if (bid >= NROUTER) {
        // ---- Wo 128x128 transpose+convert: Wot[n][k] = Wo[k][n] ----
        __shared__ _Float16 tl[128 * 128];
        int cb = bid - NROUTER;           // 0..63
        int c0 = (cb & 7) * 128, r0 = (cb >> 3) * 128;
        #pragma unroll
        for (int p = 0; p < 16; ++p) {
            int idx = p * 256 + tid;
            int rr = idx >> 5, cg = (idx & 31) * 4;
            f4 v = *(const f4*)&Wo[(size_t)(r0 + rr) * 1024 + c0 + cg];
            half4 o;
            o.x = (_Float16)v.x; o.y = (_Float16)v.y;
            o.z = (_Float16)v.z; o.w = (_Float16)v.w;
            int sc = cg ^ (((rr >> 3) & 7) << 2);
            *(half4*)&tl[rr * 128 + sc] = o;
        }
        __syncthreads();
        #pragma unroll
        for (int p = 0; p < 8; ++p) {
            int chunk = p * 256 + tid;
            int cc = chunk >> 4, ch = chunk & 15;
            int cidx = cc ^ ((ch & 7) << 2);
            half8 o;
            #pragma unroll
            for (int j = 0; j < 8; ++j)
                o[j] = tl[(ch * 8 + j) * 128 + cidx];
            *(half8*)&Wot[(size_t)(c0 + cc) * 1024 + r0 + ch * 8] = o;
        }
        return;
    }
    // ---- router: one wave per token + x->fp16 conversion fused ----
    int s = bid * 4 + (tid >> 6);
    int lane = tid & 63;
    int h = lane & 31, half = lane >> 5;
    const float* xr = x + (size_t)s * E + half * 512;
    const float* wr = Wr + (size_t)(half * 512) * H + h;
    float a0 = 0.f, a1 = 0.f, a2 = 0.f, a3 = 0.f;
    #pragma unroll 4
    for (int e = 0; e < 512; e += 4) {
        a0 += xr[e]     * wr[e * H];
        a1 += xr[e + 1] * wr[(e + 1) * H];
        a2 += xr[e + 2] * wr[(e + 2) * H];
        a3 += xr[e + 3] * wr[(e + 3) * H];
    }
    float acc = (a0 + a1) + (a2 + a3);
    acc += __shfl_xor(acc, 32, 64);
    float logit = acc;
    float m = logit;
    #pragma unroll
    for (int off = 16; off; off >>= 1) m = fmaxf(m, __shfl_xor(m, off, 64));
    float ex = expf(logit - m);
    float Z = ex;
    #pragma unroll
    for (int off = 16; off; off >>= 1) Z += __shfl_xor(Z, off, 64);
    float p = ex / Z;
    float es = p * logf(p + 1e-8f);
    #pragma unroll
    for (int off = 16; off; off >>= 1) es += __shfl_xor(es, off, 64);
    float lse = m + logf(Z);
    float lv = logit;
    float tv[KSEL]; int ti[KSEL];
    #pragma unroll
    for (int j = 0; j < KSEL; ++j) {
        float bv = lv; int bi = h;
        #pragma unroll
        for (int off = 16; off; off >>= 1) {
            float ov = __shfl_xor(bv, off, 64);
            int oi = __shfl_xor(bi, off, 64);
            if (ov > bv || (ov == bv && oi < bi)) { bv = ov; bi = oi; }
        }
        tv[j] = bv; ti[j] = bi;
        if (h == bi) lv = -INFINITY;
    }
    float Z2 = 0.f;
    #pragma unroll
    for (int j = 0; j < KSEL; ++j) Z2 += expf(tv[j] - tv[0]);
    if (lane < 32) pbuf[s * 32 + lane] = p;
    if (lane == 0) {
        entz[s * 2]     = es;
        entz[s * 2 + 1] = lse * lse;
        #pragma unroll
        for (int j = 0; j < KSEL; ++j) {
            head_idx[s * KSEL + j] = ti[j];
            head_w[s * KSEL + j]   = expf(tv[j] - tv[0]) / Z2;
        }
    }
    const float* xrow = x + (size_t)s * E;
    _Float16* xhrow = xh + (size_t)s * E;
    #pragma unroll
    for (int t = 0; t < 4; ++t) {
        int e = t * 256 + lane * 4;
        f4 v = *(const f4*)&xrow[e];
        half4 o;
        o.x = (_Float16)v.x; o.y = (_Float16)v.y; o.z = (_Float16)v.z; o.w = (_Float16)v.w;
        *(half4*)&xhrow[e] = o;
    }
}

// ---------------- scan (blocks 0..31) + aux (block 32) ----------------
__global__ __launch_bounds__(256) void scan_aux_kernel(
    const int* __restrict__ head_idx, const int* __restrict__ head_counts,
    int* __restrict__ order, int* __restrict__ hlen, float* __restrict__ out_counts,
    const float* __restrict__ pbuf, const float* __restrict__ entz,
    float* __restrict__ out_aux)
{
    int bid = blockIdx.x, tid = threadIdx.x;
    if (bid == H) {
        int hh = tid & 31, grp = tid >> 5;
        __shared__ float red[256], red2[256];
        __shared__ float psum[32];
        __shared__ int hist[32];
        if (tid < 32) hist[tid] = 0;
        float ps = 0.f;
        for (int s = grp; s < S; s += 8) ps += pbuf[s * 32 + hh];
        red[tid] = ps;
        float es = 0.f, zs = 0.f;
        for (int s = tid; s < S; s += 256) { es += entz[s * 2]; zs += entz[s * 2 + 1]; }
        red2[tid] = es;
        __syncthreads();
        if (grp == 0) {
            float v = 0.f;
            #pragma unroll
            for (int j = 0; j < 8; ++j) v += red[j * 32 + hh];
            psum[hh] = v;
        }
        __syncthreads();
        red[tid] = zs;
        for (int s = tid; s < S; s += 256)
            atomicAdd(&hist[head_idx[s * KSEL]], 1);
        __syncthreads();
        for (int stp = 128; stp; stp >>= 1) {
            if (tid < stp) { red[tid] += red[tid + stp]; red2[tid] += red2[tid + stp]; }
            __syncthreads();
        }
        if (tid == 0) {
            float bal = 0.f;
            for (int j = 0; j < H; ++j)
                bal += ((float)hist[j] / (float)S) * (psum[j] / (float)S);
            bal *= (float)H;
            float ent_loss = red2[0] / (float)S;
            float z = red[0] / (float)S * 0.01f;
            out_aux[0] = 0.01f * bal + 0.01f * ent_loss + z;
        }
        return;
    }
    int h = bid;
    int wave = tid >> 6, lane = tid & 63;
    __shared__ int wtot[4][4];
    int base = 0;
    int hc = head_counts[h];
    int v0 = head_idx[tid],       v1 = head_idx[256 + tid];
    int v2 = head_idx[512 + tid], v3 = head_idx[768 + tid];
    unsigned long long lt = (1ull << lane) - 1ull;
    for (int c0 = 0; c0 < SK; c0 += 1024) {
        int n0 = 0, n1 = 0, n2 = 0, n3 = 0;
        if (c0 + 1024 < SK) {
            n0 = head_idx[c0 + 1024 + tid]; n1 = head_idx[c0 + 1280 + tid];
            n2 = head_idx[c0 + 1536 + tid]; n3 = head_idx[c0 + 1792 + tid];
        }
        bool p0 = (v0 == h), p1 = (v1 == h), p2 = (v2 == h), p3 = (v3 == h);
        unsigned long long m0 = __ballot(p0), m1 = __ballot(p1);
        unsigned long long m2 = __ballot(p2), m3 = __ballot(p3);
        int w0 = __popcll(m0 & lt), w1 = __popcll(m1 & lt);
        int w2 = __popcll(m2 & lt), w3 = __popcll(m3 & lt);
        if (lane == 0) {
            wtot[0][wave] = __popcll(m0); wtot[1][wave] = __popcll(m1);
            wtot[2][wave] = __popcll(m2); wtot[3][wave] = __popcll(m3);
        }
        __syncthreads();
        int pw[4], T[4];
        #pragma unroll
        for (int i = 0; i < 4; ++i) {
            int pre = 0, tot = 0;
            #pragma unroll
            for (int w = 0; w < 4; ++w) {
                int tv = wtot[i][w];
                if (w < wave) pre += tv;
                tot += tv;
            }
            pw[i] = pre; T[i] = tot;
        }
        if (p0) order[h * MAXL + base + pw[0] + w0] = c0 + tid;
        if (p1) order[h * MAXL + base + T[0] + pw[1] + w1] = c0 + 256 + tid;
        if (p2) order[h * MAXL + base + T[0] + T[1] + pw[2] + w2] = c0 + 512 + tid;
        if (p3) order[h * MAXL + base + T[0] + T[1] + T[2] + pw[3] + w3] = c0 + 768 + tid;
        base += T[0] + T[1] + T[2] + T[3];
        __syncthreads();
        v0 = n0; v1 = n1; v2 = n2; v3 = n3;
    }
    if (tid == 0) {
        hlen[h] = base;
        out_counts[h] = (float)(hc + base);
    }
}

// ================= qkv direct-from-f32: whole weight panel resident in LDS ==========
// grid 192 = proj(3) x head(32) x colhalf(2); 512 threads (8 waves), 1 block/CU.
// Column sets: hs=0 -> {0..31, 64..95}, hs=1 -> {32..63, 96..127} so the RoPE pair
// (d, d+64) lands in acc[..][nf=0]/acc[..][nf=1] of the SAME lane -> RoPE in registers.
// B panel: 64 cols x 1024 k f16 staged in two 64KB halves, XOR-swizzled; K-loop has
// no barriers (B read-only after stage). Deletes the Wq/Wk/Wv f32->f16 conv stage.
__global__ __launch_bounds__(512) void qkv_direct(
    const _Float16* __restrict__ xh,
    const float* __restrict__ Wq, const float* __restrict__ Wk, const float* __restrict__ Wv,
    const int* __restrict__ order, const int* __restrict__ hlen,
    const int* __restrict__ head_counts, const float2* __restrict__ tab,
    _Float16* __restrict__ qh, _Float16* __restrict__ kh, _Float16* __restrict__ vT)
{
    int bid = blockIdx.x;
    int hs = bid & 1;
    int h  = (bid >> 1) & 31;
    int z  = bid >> 6;
    const float* W = (z == 0) ? Wq : (z == 1) ? Wk : Wv;

    int len = hlen[h];
    int hb = 0;
    for (int i = 0; i < h; ++i) hb += (hlen[i] + 31) & ~31;
    int lenp = (len + 31) & ~31;

    int tid = threadIdx.x;
    int wv = tid >> 6;            // wave 0..7
    int lane = tid & 63;
    int l32 = lane & 31, g = lane >> 5;

    __shared__ _Float16 Bsh[64 * 512];   // 64KB: [logical col][k within half], XOR swizzle

    // staging column mapping (logical 0..63 -> physical 0..127)
    int scol = tid & 63;
    int pscol = ((scol >> 5) << 6) + hs * 32 + (scol & 31);
    const float* wcol = W + (size_t)h * D + pscol;

    int npass = (len > 512) ? 2 : 1;
    int tok[2][2];
    #pragma unroll
    for (int p = 0; p < 2; ++p)
        #pragma unroll
        for (int rt = 0; rt < 2; ++rt) {
            int r = p * 512 + wv * 64 + rt * 32 + l32;
            tok[p][rt] = (r < len) ? (order[h * MAXL + r] >> 3) : 0;
        }

    floatx16 acc[2][2][2] = {};   // [pass][row-tile][col-frag]

    for (int khf = 0; khf < 2; ++khf) {
        int kbase = khf * 512;
        if (khf) __syncthreads();          // waves done reading Bsh half 0
        {
            // stage W[kbase..kbase+512) x 64 cols: lane-coalesced 128B row segments,
            // pack 8 k-values per thread -> one b128 ds_write (bank-quads spread by col&7)
            int eg = tid >> 6;
            const float* wp = wcol + (size_t)(kbase + eg * 8) * HD;
            for (int rnd = 0; rnd < 8; ++rnd) {
                float v[8];
                #pragma unroll
                for (int j = 0; j < 8; ++j) v[j] = wp[(size_t)j * HD];
                half8 o;
                #pragma unroll
                for (int j = 0; j < 8; ++j) o[j] = (_Float16)v[j];
                int e0 = rnd * 64 + eg * 8;
                *(half8*)&Bsh[scol * 512 + (e0 ^ ((scol & 7) << 3))] = o;
                wp += (size_t)64 * HD;
            }
        }
        __syncthreads();
        #pragma unroll
        for (int p = 0; p < 2; ++p) {
            if (p < npass) {
                const _Float16* ap0 = xh + (size_t)tok[p][0] * E + kbase + g * 8;
                const _Float16* ap1 = xh + (size_t)tok[p][1] * E + kbase + g * 8;
                #pragma unroll 2
                for (int kb = 0; kb < 8; ++kb) {
                    half8 A0[4], A1[4];
                    #pragma unroll
                    for (int kc = 0; kc < 4; ++kc) {
                        A0[kc] = *(const half8*)(ap0 + kb * 64 + kc * 16);
                        A1[kc] = *(const half8*)(ap1 + kb * 64 + kc * 16);
                    }
                    #pragma unroll
                    for (int kc = 0; kc < 4; ++kc) {
                        int kk = kb * 64 + kc * 16 + g * 8;
                        int kkx = kk ^ ((l32 & 7) << 3);
                        half8 b0 = *(const half8*)&Bsh[l32 * 512 + kkx];
                        half8 b1 = *(const half8*)&Bsh[(32 + l32) * 512 + kkx];
                        acc[p][0][0] = __builtin_amdgcn_mfma_f32_32x32x16_f16(A0[kc], b0, acc[p][0][0], 0, 0, 0);
                        acc[p][0][1] = __builtin_amdgcn_mfma_f32_32x32x16_f16(A0[kc], b1, acc[p][0][1], 0, 0, 0);
                        acc[p][1][0] = __builtin_amdgcn_mfma_f32_32x32x16_f16(A1[kc], b0, acc[p][1][0], 0, 0, 0);
                        acc[p][1][1] = __builtin_amdgcn_mfma_f32_32x32x16_f16(A1[kc], b1, acc[p][1][1], 0, 0, 0);
                    }
                }
            }
        }
    }

    if (z < 2) {
        // RoPE in registers: v1 = acc[..][0][reg] (col d2), v2 = acc[..][1][reg] (col d2+64)
        _Float16* dst = (z == 0) ? qh : kh;
        int hc = head_counts[h];
        int d2 = hs * 32 + l32;
        #pragma unroll
        for (int p = 0; p < 2; ++p) {
            if (p < npass) {
                #pragma unroll
                for (int rt = 0; rt < 2; ++rt) {
                    int base = p * 512 + wv * 64 + rt * 32;
                    #pragma unroll
                    for (int reg = 0; reg < 16; ++reg) {
                        int slot = base + (reg & 3) + 8 * (reg >> 2) + 4 * g;
                        if (slot < len) {
                            int pos = slot + hc;
                            pos = pos < 0 ? 0 : (pos > 8191 ? 8191 : pos);
                            float2 tt = tab[pos * 64 + d2];
                            float v1 = acc[p][rt][0][reg], v2 = acc[p][rt][1][reg];
                            _Float16* dp = dst + ((size_t)hb + slot) * D;
                            dp[d2]      = (_Float16)(v1 * tt.x - v2 * tt.y);
                            dp[d2 + 64] = (_Float16)(v2 * tt.x + v1 * tt.y);
                        }
                    }
                }
            }
        }
    } else {
        #pragma unroll
        for (int p = 0; p < 2; ++p) {
            if (p < npass) {
                #pragma unroll
                for (int rt = 0; rt < 2; ++rt) {
                    int base = p * 512 + wv * 64 + rt * 32;
                    #pragma unroll
                    for (int nf = 0; nf < 2; ++nf) {
                        int pcol = nf * 64 + hs * 32 + l32;
                        _Float16* vp0 = vT + (size_t)hb * D + (size_t)pcol * lenp;
                        #pragma unroll
                        for (int q4 = 0; q4 < 4; ++q4) {
                            int slot0 = base + 8 * q4 + 4 * g;
                            if (slot0 + 3 < len) {
                                half4 o;
                                o.x = (_Float16)acc[p][rt][nf][q4 * 4 + 0];
                                o.y = (_Float16)acc[p][rt][nf][q4 * 4 + 1];
                                o.z = (_Float16)acc[p][rt][nf][q4 * 4 + 2];
                                o.w = (_Float16)acc[p][rt][nf][q4 * 4 + 3];
                                *(half4*)(vp0 + slot0) = o;
                            } else {
                                #pragma unroll
                                for (int r2 = 0; r2 < 4; ++r2) {
                                    int sl = slot0 + r2;
                                    if (sl < len) vp0[sl] = (_Float16)acc[p][rt][nf][q4 * 4 + r2];
                                    else if (sl < lenp) vp0[sl] = (_Float16)0.f;   // keep pad NaN-free
                                }
                            }
                        }
                    }
                }
            }
        }
    }
}

// ---------------- per-head causal flash attention: 2-wave split-K, MFMA 32x32x16 ----------------
__global__ __launch_bounds__(128) void attn_mfma(
    const _Float16* __restrict__ qh, const _Float16* __restrict__ kh,
    const _Float16* __restrict__ vT,
    const int* __restrict__ order, const int* __restrict__ hlen,
    const float* __restrict__ head_w, _Float16* __restrict__ ao)
{
    int h = blockIdx.x >> 5, qt = blockIdx.x & 31;
    int len = hlen[h];
    int row0 = qt * 32;
    if (row0 >= len) return;
    int hb = 0;
    for (int i = 0; i < h; ++i) hb += (hlen[i] + 31) & ~31;
    int lenp = (len + 31) & ~31;
    int tid = threadIdx.x;
    int w = tid >> 6, lane = tid & 63;
    int l32 = lane & 31, g = lane >> 5;
    int srow = lane >> 1, shalf = lane & 1;

    __shared__ float Sld[2][32 * SSTR];
    __shared__ _Float16 Pld[2][32 * PSTR];
    __shared__ float alphaLd[2][32];
    __shared__ float mlLd[32][4];     // m0,l0,m1,l1
    __shared__ float facLd[32][3];    // f1, hw/l*, f0
    __shared__ int flatLd[32];
    __shared__ float Obuf[32][128];

    if (tid < 32) {
        int r = row0 + tid;
        flatLd[tid] = (r < len) ? order[h * MAXL + r] : -1;
    }

    const _Float16* qrow = qh + ((size_t)hb + row0 + l32) * D;
    half8 qf[8];
    #pragma unroll
    for (int t = 0; t < 8; ++t) qf[t] = *(const half8*)(qrow + t * 16 + g * 8);

    floatx16 O[4] = {};
    float m_run = -INFINITY, l_run = 0.f;

    if (w <= qt) {
        half8 kf[8], kfn[8], vv[8];
        {
            const _Float16* krow = kh + ((size_t)hb + w * 32 + l32) * D;
            #pragma unroll
            for (int t = 0; t < 8; ++t) kf[t] = *(const half8*)(krow + t * 16 + g * 8);
        }
        for (int kt = w; kt <= qt; kt += 2) {
            int col0 = kt * 32;
            floatx16 Sc = {};
            #pragma unroll
            for (int t = 0; t < 8; ++t)
                Sc = __builtin_amdgcn_mfma_f32_32x32x16_f16(qf[t], kf[t], Sc, 0, 0, 0);
            #pragma unroll
            for (int nt = 0; nt < 4; ++nt) {
                const _Float16* vp = vT + (size_t)hb * D + (size_t)(nt * 32 + l32) * lenp + col0;
                vv[nt * 2]     = *(const half8*)(vp + g * 8);
                vv[nt * 2 + 1] = *(const half8*)(vp + 16 + g * 8);
            }
            if (kt + 2 <= qt) {
                const _Float16* krow = kh + ((size_t)hb + col0 + 64 + l32) * D;
                #pragma unroll
                for (int t = 0; t < 8; ++t) kfn[t] = *(const half8*)(krow + t * 16 + g * 8);
            }
            bool diag = (kt == qt);
            #pragma unroll
            for (int reg = 0; reg < 16; ++reg) {
                int row = (reg & 3) + 8 * (reg >> 2) + 4 * g;
                float s = Sc[reg] * ATTN_SCALE;
                if (diag && l32 > row) s = -1e30f;
                Sld[w][row * SSTR + l32] = s;
            }
            __builtin_amdgcn_wave_barrier();
            const float* sp = &Sld[w][srow * SSTR + shalf * 16];
            float va[16];
            *(f4*)(va)      = *(const f4*)(sp);
            *(f4*)(va + 4)  = *(const f4*)(sp + 4);
            *(f4*)(va + 8)  = *(const f4*)(sp + 8);
            *(f4*)(va + 12) = *(const f4*)(sp + 12);
            float mt_ = va[0];
            #pragma unroll
            for (int j = 1; j < 16; ++j) mt_ = fmaxf(mt_, va[j]);
            mt_ = fmaxf(mt_, __shfl_xor(mt_, 1, 64));
            float m_new = fmaxf(m_run, mt_);
            float alpha = __expf(m_run - m_new);
            float p[16], tsum = 0.f;
            #pragma unroll
            for (int j = 0; j < 16; ++j) { p[j] = __expf(va[j] - m_new); tsum += p[j]; }
            tsum += __shfl_xor(tsum, 1, 64);
            l_run = l_run * alpha + tsum;
            m_run = m_new;
            half8 ph0, ph1;
            #pragma unroll
            for (int j = 0; j < 8; ++j) { ph0[j] = (_Float16)p[j]; ph1[j] = (_Float16)p[j + 8]; }
            *(half8*)&Pld[w][srow * PSTR + shalf * 16]     = ph0;
            *(half8*)&Pld[w][srow * PSTR + shalf * 16 + 8] = ph1;
            if (shalf == 0) alphaLd[w][srow] = alpha;
            __builtin_amdgcn_wave_barrier();
            f4 al[4];
            #pragma unroll
            for (int qq = 0; qq < 4; ++qq) al[qq] = *(const f4*)&alphaLd[w][4 * g + 8 * qq];
            #pragma unroll
            for (int reg = 0; reg < 16; ++reg) {
                float av = al[reg >> 2][reg & 3];
                O[0][reg] *= av; O[1][reg] *= av; O[2][reg] *= av; O[3][reg] *= av;
            }
            half8 pf0 = *(const half8*)&Pld[w][l32 * PSTR + g * 8];
            half8 pf1 = *(const half8*)&Pld[w][l32 * PSTR + 16 + g * 8];
            #pragma unroll
            for (int nt = 0; nt < 4; ++nt) {
                O[nt] = __builtin_amdgcn_mfma_f32_32x32x16_f16(pf0, vv[nt * 2],     O[nt], 0, 0, 0);
                O[nt] = __builtin_amdgcn_mfma_f32_32x32x16_f16(pf1, vv[nt * 2 + 1], O[nt], 0, 0, 0);
            }
            __builtin_amdgcn_wave_barrier();
            #pragma unroll
            for (int t = 0; t < 8; ++t) kf[t] = kfn[t];
        }
    }
    // ---- merge the two waves' partial (m, l, O) ----
    if (shalf == 0) { mlLd[srow][w * 2] = m_run; mlLd[srow][w * 2 + 1] = l_run; }
    __syncthreads();
    if (tid < 32) {
        float m0 = mlLd[tid][0], l0 = mlLd[tid][1];
        float m1 = mlLd[tid][2], l1 = mlLd[tid][3];
        float ms = fmaxf(m0, m1);
        float f0 = __expf(m0 - ms), f1 = __expf(m1 - ms);
        float lt = f0 * l0 + f1 * l1;
        int flat = flatLd[tid];
        float hw = (flat >= 0) ? head_w[flat] : 0.f;
        facLd[tid][0] = f1;
        facLd[tid][1] = hw / lt;
        facLd[tid][2] = f0;
    }
    __syncthreads();
    if (w == 1) {
        #pragma unroll
        for (int nt = 0; nt < 4; ++nt) {
            int col = nt * 32 + l32;
            #pragma unroll
            for (int reg = 0; reg < 16; ++reg) {
                int row = (reg & 3) + 8 * (reg >> 2) + 4 * g;
                Obuf[row][col] = O[nt][reg] * facLd[row][0];
            }
        }
    }
    __syncthreads();
    if (w == 0) {
        #pragma unroll
        for (int nt = 0; nt < 4; ++nt) {
            int col = nt * 32 + l32;
            #pragma unroll
            for (int reg = 0; reg < 16; ++reg) {
                int row = (reg & 3) + 8 * (reg >> 2) + 4 * g;
                int flat = flatLd[row];
                if (flat >= 0) {
                    float val = (O[nt][reg] * facLd[row][2] + Obuf[row][col]) * facLd[row][1];
                    ao[(size_t)flat * D + col] = (_Float16)val;
                }
            }
        }
    }
}

// ---------------- output projection: B-only LDS dbuf MFMA GEMM, A direct-to-reg ----------------
__global__ __launch_bounds__(256) void out_mfma(
    const _Float16* __restrict__ A, const _Float16* __restrict__ Bt,
    float* __restrict__ C)
{
    int n0 = blockIdx.x * 64, m0 = blockIdx.y * 64;
    int tid = threadIdx.x, wave = tid >> 6, lane = tid & 63;
    int wm = wave >> 1, wn = wave & 1;
    int l32 = lane & 31, g = lane >> 5;

    __shared__ _Float16 Bs[2][64 * 64];

    const _Float16* aptr = A + (size_t)(m0 + wm * 32 + l32) * 1024;

    auto stageB = [&](int buf, int k0) {
        #pragma unroll
        for (int it = 0; it < 2; ++it) {
            int f = it * 256 + tid;
            int row = f >> 3, c = f & 7;
            int sc = c ^ (row & 7);
            GLOAD_LDS16(Bt + (size_t)(n0 + row) * 1024 + k0 + sc * 8, &Bs[buf][f * 8]);
        }
    };

    floatx16 acc = {};
    int brow = wn * 32 + l32;
    half8 a_cur[4], a_nxt[4];
    #pragma unroll
    for (int ks = 0; ks < 4; ++ks)
        a_cur[ks] = *(const half8*)(aptr + ks * 16 + g * 8);

    auto compute = [&](int buf, half8* a) {
        #pragma unroll
        for (int ks = 0; ks < 4; ++ks) {
            int wchunk = ks * 2 + g;
            half8 bf = *(const half8*)&Bs[buf][brow * 64 + (wchunk ^ (brow & 7)) * 8];
            acc = __builtin_amdgcn_mfma_f32_32x32x16_f16(a[ks], bf, acc, 0, 0, 0);
        }
    };

    stageB(0, 0);
    __syncthreads();
    int buf = 0;
    for (int k0 = 64; k0 < 1024; k0 += 64) {
        stageB(buf ^ 1, k0);
        #pragma unroll
        for (int ks = 0; ks < 4; ++ks)
            a_nxt[ks] = *(const half8*)(aptr + k0 + ks * 16 + g * 8);
        compute(buf, a_cur);
        __syncthreads();
        buf ^= 1;
        #pragma unroll
        for (int ks = 0; ks < 4; ++ks) a_cur[ks] = a_nxt[ks];
    }
    compute(buf, a_cur);

    int col = n0 + wn * 32 + l32;
    #pragma unroll
    for (int reg = 0; reg < 16; ++reg) {
        int row = m0 + wm * 32 + (reg & 3) + 8 * (reg >> 2) + 4 * g;
        C[(size_t)row * 1024 + col] = acc[reg];
    }
}

extern "C" void kernel_launch(void* const* d_in, const int* in_sizes, int n_in,
                              void* d_out, int out_size, void* d_ws, size_t ws_size,
                              hipStream_t stream)
{
    const float* x  = (const float*)d_in[0];
    const float* Wq = (const float*)d_in[1];
    const float* Wk = (const float*)d_in[2];
    const float* Wv = (const float*)d_in[3];
    const float* Wr = (const float*)d_in[4];
    const float* Wo = (const float*)d_in[5];
    const int* head_counts = (const int*)d_in[6];
    float* out = (float*)d_out;

    float* head_w = (float*)d_ws;                 // SK
    float* pbuf   = head_w + SK;                  // S*32
    float* entz   = pbuf + S * 32;                // S*2
    int* head_idx = (int*)(entz + S * 2);         // SK
    int* order    = head_idx + SK;                // H*MAXL
    int* hlen     = order + H * MAXL;             // 32 (pad 64)
    _Float16* xh   = (_Float16*)(hlen + 64);      // S*E
    _Float16* aoh  = xh + (size_t)S * E;          // SK*D
    _Float16* Wot  = aoh + (size_t)SK * D;        // 1024*1024
    _Float16* qh   = Wot + (size_t)1024 * 1024;   // CAP*D
    _Float16* kh   = qh + (size_t)CAP * D;        // CAP*D
    _Float16* vT   = kh + (size_t)CAP * D;        // CAP*D
    float2* tab    = (float2*)(vT + (size_t)CAP * D);   // 8192*64 float2 = 4MB

    router_conv_kernel<<<NROUTER + NCONV + NTAB, 256, 0, stream>>>(
        x, Wr, head_idx, head_w, pbuf, entz, xh, Wo, Wot, tab);
    scan_aux_kernel<<<33, 256, 0, stream>>>(head_idx, head_counts, order, hlen,
                                            out + (size_t)S * E, pbuf, entz,
                                            out + (size_t)S * E + H);
    qkv_direct<<<192, 512, 0, stream>>>(xh, Wq, Wk, Wv, order, hlen, head_counts, tab,
                                        qh, kh, vT);
    attn_mfma<<<H * 32, 128, 0, stream>>>(qh, kh, vT, order, hlen, head_w, aoh);
    out_mfma<<<dim3(16, 16), 256, 0, stream>>>(aoh, Wot, out);
}